// Round 4
// baseline (430.579 us; speedup 1.0000x reference)
//
#include <hip/hip_runtime.h>
#include <hip/hip_bf16.h>
#include <math.h>

#define DIM 1024
#define NEXP 8

typedef float fv4 __attribute__((ext_vector_type(4)));

// ---------------------------------------------------------------------------
// Kernel 0: branch-free nontemporal zero of a contiguous 16B-vector region.
// Covers expert_weights + expert_mask (they are adjacent in d_out).
// ---------------------------------------------------------------------------
__global__ __launch_bounds__(256) void k_zero(fv4* __restrict__ dst,
                                              size_t n4)
{
    const fv4 z = {0.f, 0.f, 0.f, 0.f};
    size_t i = (size_t)blockIdx.x * 256 + threadIdx.x;
    const size_t stride = (size_t)gridDim.x * 256;
    for (; i < n4; i += stride)
        __builtin_nontemporal_store(z, &dst[i]);
}

// ---------------------------------------------------------------------------
// Kernel 1: router logits + top-2 + 2-way softmax.
// 256 threads = 4 waves; each wave computes 4 tokens sequentially so the
// 32 KB w_gate LDS staging is amortized over 16 tokens/block.
// ---------------------------------------------------------------------------
__global__ __launch_bounds__(256) void k_router(
    const float* __restrict__ x, const float* __restrict__ wg,
    float* __restrict__ logits,
    int* __restrict__ e1, int* __restrict__ e2,
    float* __restrict__ p1, float* __restrict__ p2, int N)
{
    __shared__ float wlds[NEXP * DIM];
    const int tid = threadIdx.x;
    for (int i = tid; i < NEXP * DIM; i += 256) wlds[i] = wg[i];
    __syncthreads();

    const int wave = tid >> 6, lane = tid & 63;

    for (int t = 0; t < 4; ++t) {
        const int n = blockIdx.x * 16 + wave * 4 + t;
        if (n >= N) return;

        const float4* x4 = (const float4*)x + (size_t)n * (DIM / 4);
        float s[NEXP];
#pragma unroll
        for (int e = 0; e < NEXP; ++e) s[e] = 0.0f;

#pragma unroll
        for (int i = 0; i < 4; ++i) {
            const int idx = lane + 64 * i;
            const float4 v = x4[idx];
#pragma unroll
            for (int e = 0; e < NEXP; ++e) {
                const float* wrow = &wlds[e * DIM + idx * 4];
                float acc = s[e];
                acc = fmaf(v.x, wrow[0], acc);
                acc = fmaf(v.y, wrow[1], acc);
                acc = fmaf(v.z, wrow[2], acc);
                acc = fmaf(v.w, wrow[3], acc);
                s[e] = acc;
            }
        }

#pragma unroll
        for (int off = 32; off >= 1; off >>= 1) {
#pragma unroll
            for (int e = 0; e < NEXP; ++e) s[e] += __shfl_xor(s[e], off, 64);
        }

        // top-2, lowest-index tie-break (matches jax.lax.top_k)
        int be1 = 0; float bv1 = s[0];
#pragma unroll
        for (int e = 1; e < NEXP; ++e) { if (s[e] > bv1) { bv1 = s[e]; be1 = e; } }
        int be2 = -1; float bv2 = -INFINITY;
#pragma unroll
        for (int e = 0; e < NEXP; ++e) { if (e != be1 && s[e] > bv2) { bv2 = s[e]; be2 = e; } }

        const float tt = expf(bv2 - bv1);      // <= 1
        const float inv = 1.0f / (1.0f + tt);

        if (lane == 0) {
#pragma unroll
            for (int e = 0; e < NEXP; ++e) logits[(size_t)n * NEXP + e] = s[e];
            e1[n] = be1; e2[n] = be2;
            p1[n] = inv; p2[n] = tt * inv;
        }
    }
}

// ---------------------------------------------------------------------------
// Kernel 2: parallel k-major rank scan + sparse injection.
// Single block, 1024 threads = 16 waves.
//   Phase A: per 64-token chunk, per-expert 64-bit membership ballots -> LDS.
//   Phase B: Hillis-Steele inclusive prefix over chunk dim (stride NEXP).
//   Phase C: rank = excl_base + popcount(mask & below); if rank < cap,
//            scatter p / mask-bit directly into the (pre-zeroed) W and M
//            arrays and record slot_token for the batches kernel.
// ---------------------------------------------------------------------------
__global__ __launch_bounds__(1024) void k_scan(
    const int* __restrict__ e1, const int* __restrict__ e2,
    const float* __restrict__ p1, const float* __restrict__ p2,
    float* __restrict__ W, float* __restrict__ M,
    int* __restrict__ slot_token, int N, int cap)
{
    __shared__ unsigned long long emask[128 * NEXP];  // 8 KB
    __shared__ int pre[128 * NEXP];                   // 4 KB

    const int tid = threadIdx.x;
    const int wave = tid >> 6, lane = tid & 63;
    const int cpk = N / 64;             // chunks per k (64 for N=4096)
    const int nchunks = 2 * cpk;        // 128
    const int nelem = nchunks * NEXP;   // 1024

    for (int i = tid; i < NEXP * cap; i += 1024) slot_token[i] = -1;

    // Phase A
    for (int c = wave; c < nchunks; c += 16) {
        const int k = c / cpk, r = c % cpk;
        const int n = r * 64 + lane;
        const int e = (k == 0 ? e1 : e2)[n];
#pragma unroll
        for (int q = 0; q < NEXP; ++q) {
            const unsigned long long b = __ballot(e == q);
            if (lane == q) emask[c * NEXP + q] = b;
        }
    }
    __syncthreads();

    // Phase B
    if (tid < nelem) pre[tid] = (int)__popcll(emask[tid]);
    __syncthreads();
    for (int off = NEXP; off < nelem; off <<= 1) {
        int add = 0;
        if (tid < nelem && tid >= off) add = pre[tid - off];
        __syncthreads();
        if (tid < nelem) pre[tid] += add;
        __syncthreads();
    }

    // Phase C
    const unsigned long long below =
        (lane == 0) ? 0ULL : ((~0ULL) >> (64 - lane));
    for (int c = wave; c < nchunks; c += 16) {
        const int k = c / cpk, r = c % cpk;
        const int n = r * 64 + lane;
        const float p = (k == 0 ? p1 : p2)[n];
        int e = 0; unsigned long long mm = 0;
#pragma unroll
        for (int q = 0; q < NEXP; ++q) {
            const unsigned long long b = emask[c * NEXP + q];
            if ((b >> lane) & 1ULL) { e = q; mm = b; }
        }
        const int bexc = (c > 0) ? pre[(c - 1) * NEXP + e] : 0;
        const int rank = bexc + (int)__popcll(mm & below);
        if (rank < cap) {
            const size_t off = ((size_t)n * NEXP + e) * cap + rank;
            W[off] = p;
            M[off] = (p > 0.0f) ? 1.0f : 0.0f;
            slot_token[(size_t)e * cap + rank] = (p > 0.0f) ? n : -1;
        }
    }
}

// ---------------------------------------------------------------------------
// Kernel 3: fill expert_batches. One wave per (e,slot) row: copy x[tok] or
// zeros. D = 1024 floats = 256 x 16B = 4 iters of 64 lanes.
// ---------------------------------------------------------------------------
__global__ __launch_bounds__(256) void k_batches(
    const int* __restrict__ slot_token, const float* __restrict__ x,
    float* __restrict__ Bt, int nrows)
{
    const int wave = threadIdx.x >> 6, lane = threadIdx.x & 63;
    const int row = blockIdx.x * 4 + wave;
    if (row >= nrows) return;

    const int tok = slot_token[row];
    fv4* out = (fv4*)(Bt + (size_t)row * DIM);
    if (tok >= 0) {
        const fv4* src = (const fv4*)(x + (size_t)tok * DIM);
#pragma unroll
        for (int i = 0; i < 4; ++i)
            __builtin_nontemporal_store(src[lane + 64 * i], &out[lane + 64 * i]);
    } else {
        const fv4 z = {0.f, 0.f, 0.f, 0.f};
#pragma unroll
        for (int i = 0; i < 4; ++i)
            __builtin_nontemporal_store(z, &out[lane + 64 * i]);
    }
}

// ---------------------------------------------------------------------------
extern "C" void kernel_launch(void* const* d_in, const int* in_sizes, int n_in,
                              void* d_out, int out_size, void* d_ws, size_t ws_size,
                              hipStream_t stream)
{
    const float* x  = (const float*)d_in[0];
    const float* wg = (const float*)d_in[1];

    const int N = in_sizes[0] / DIM;          // 4096 tokens
    int cap = (5 * N) / 16;                   // floor(2*1.25*N/8)
    cap += cap & 1;
    if (cap < 2) cap = 2;

    // output layout: W [N,E,cap] | M [N,E,cap] | Bt [E,cap,D] | L [N,E]
    const size_t szW = (size_t)N * NEXP * cap;
    float* W  = (float*)d_out;
    float* M  = W + szW;
    float* Bt = M + szW;
    float* L  = Bt + (size_t)NEXP * cap * DIM;

    // workspace carve-up
    char* w = (char*)d_ws;
    int*   e1 = (int*)w;        w += (size_t)N * sizeof(int);
    int*   e2 = (int*)w;        w += (size_t)N * sizeof(int);
    float* p1 = (float*)w;      w += (size_t)N * sizeof(float);
    float* p2 = (float*)w;      w += (size_t)N * sizeof(float);
    int*   slot_token = (int*)w;

    // zero W+M (contiguous, 2*szW floats)
    const size_t n4 = (2 * szW) / 4;
    k_zero<<<4096, 256, 0, stream>>>((fv4*)W, n4);

    k_router<<<(N + 15) / 16, 256, 0, stream>>>(x, wg, L, e1, e2, p1, p2, N);
    k_scan<<<1, 1024, 0, stream>>>(e1, e2, p1, p2, W, M, slot_token, N, cap);

    const int nrows_b = NEXP * cap;
    k_batches<<<(nrows_b + 3) / 4, 256, 0, stream>>>(slot_token, x, Bt, nrows_b);
}

// Round 5
// 403.341 us; speedup vs baseline: 1.0675x; 1.0675x over previous
//
#include <hip/hip_runtime.h>
#include <hip/hip_bf16.h>
#include <math.h>

#define DIM 1024
#define NEXP 8

typedef float fv4 __attribute__((ext_vector_type(4)));

// ---------------------------------------------------------------------------
// Kernel 1: router logits + top-2 + 2-way softmax.
// 256 threads = 4 waves; each wave computes 4 tokens sequentially so the
// 32 KB w_gate LDS staging is amortized over 16 tokens/block.
// ---------------------------------------------------------------------------
__global__ __launch_bounds__(256) void k_router(
    const float* __restrict__ x, const float* __restrict__ wg,
    float* __restrict__ logits,
    int* __restrict__ e1, int* __restrict__ e2,
    float* __restrict__ p1, float* __restrict__ p2, int N)
{
    __shared__ float wlds[NEXP * DIM];
    const int tid = threadIdx.x;
    for (int i = tid; i < NEXP * DIM; i += 256) wlds[i] = wg[i];
    __syncthreads();

    const int wave = tid >> 6, lane = tid & 63;

    for (int t = 0; t < 4; ++t) {
        const int n = blockIdx.x * 16 + wave * 4 + t;
        if (n >= N) return;

        const float4* x4 = (const float4*)x + (size_t)n * (DIM / 4);
        float s[NEXP];
#pragma unroll
        for (int e = 0; e < NEXP; ++e) s[e] = 0.0f;

#pragma unroll
        for (int i = 0; i < 4; ++i) {
            const int idx = lane + 64 * i;
            const float4 v = x4[idx];
#pragma unroll
            for (int e = 0; e < NEXP; ++e) {
                const float* wrow = &wlds[e * DIM + idx * 4];
                float acc = s[e];
                acc = fmaf(v.x, wrow[0], acc);
                acc = fmaf(v.y, wrow[1], acc);
                acc = fmaf(v.z, wrow[2], acc);
                acc = fmaf(v.w, wrow[3], acc);
                s[e] = acc;
            }
        }

#pragma unroll
        for (int off = 32; off >= 1; off >>= 1) {
#pragma unroll
            for (int e = 0; e < NEXP; ++e) s[e] += __shfl_xor(s[e], off, 64);
        }

        // top-2, lowest-index tie-break (matches jax.lax.top_k)
        int be1 = 0; float bv1 = s[0];
#pragma unroll
        for (int e = 1; e < NEXP; ++e) { if (s[e] > bv1) { bv1 = s[e]; be1 = e; } }
        int be2 = -1; float bv2 = -INFINITY;
#pragma unroll
        for (int e = 0; e < NEXP; ++e) { if (e != be1 && s[e] > bv2) { bv2 = s[e]; be2 = e; } }

        const float tt = expf(bv2 - bv1);      // <= 1
        const float inv = 1.0f / (1.0f + tt);

        if (lane == 0) {
#pragma unroll
            for (int e = 0; e < NEXP; ++e) logits[(size_t)n * NEXP + e] = s[e];
            e1[n] = be1; e2[n] = be2;
            p1[n] = inv; p2[n] = tt * inv;
        }
    }
}

// ---------------------------------------------------------------------------
// Kernel 2: parallel k-major rank scan. Single block, 1024 threads = 16 waves.
//   Phase A: per 64-token chunk, per-expert 64-bit membership ballots -> LDS.
//   Phase B: one wave per expert, 6-step shuffle inclusive prefix over the
//            chunk counts (<= 128 chunks). Only 2 __syncthreads total.
//   Phase C: rank = excl_base + popcount(mask & below) -> r1/r2, slot_token.
// ---------------------------------------------------------------------------
__global__ __launch_bounds__(1024) void k_scan(
    const int* __restrict__ e1, const int* __restrict__ e2,
    const float* __restrict__ p1, const float* __restrict__ p2,
    int* __restrict__ r1, int* __restrict__ r2,
    int* __restrict__ slot_token, int N, int cap)
{
    __shared__ unsigned long long emask[128 * NEXP];  // 8 KB
    __shared__ int pre[128 * NEXP];                   // 4 KB

    const int tid = threadIdx.x;
    const int wave = tid >> 6, lane = tid & 63;
    const int cpk = N / 64;             // chunks per k (64 for N=4096)
    const int nchunks = 2 * cpk;        // 128 for N=4096 (<=128 required)

    for (int i = tid; i < NEXP * cap; i += 1024) slot_token[i] = -1;

    // Phase A
    for (int c = wave; c < nchunks; c += 16) {
        const int k = c / cpk, r = c % cpk;
        const int n = r * 64 + lane;
        const int e = (k == 0 ? e1 : e2)[n];
#pragma unroll
        for (int q = 0; q < NEXP; ++q) {
            const unsigned long long b = __ballot(e == q);
            if (lane == q) emask[c * NEXP + q] = b;
        }
    }
    __syncthreads();

    // Phase B: wave w (< NEXP) computes inclusive prefix for expert w
    if (wave < NEXP) {
        const int e = wave;
        int v0 = (lane < nchunks) ? (int)__popcll(emask[lane * NEXP + e]) : 0;
        int v1 = (64 + lane < nchunks)
                   ? (int)__popcll(emask[(64 + lane) * NEXP + e]) : 0;
#pragma unroll
        for (int off = 1; off < 64; off <<= 1) {
            const int t0 = __shfl_up(v0, off, 64);
            const int t1 = __shfl_up(v1, off, 64);
            if (lane >= off) { v0 += t0; v1 += t1; }
        }
        v1 += __shfl(v0, 63, 64);
        if (lane < nchunks) pre[lane * NEXP + e] = v0;
        if (64 + lane < nchunks) pre[(64 + lane) * NEXP + e] = v1;
    }
    __syncthreads();

    // Phase C
    const unsigned long long below =
        (lane == 0) ? 0ULL : ((~0ULL) >> (64 - lane));
    for (int c = wave; c < nchunks; c += 16) {
        const int k = c / cpk, r = c % cpk;
        const int n = r * 64 + lane;
        const float p = (k == 0 ? p1 : p2)[n];
        int e = 0; unsigned long long mm = 0;
#pragma unroll
        for (int q = 0; q < NEXP; ++q) {
            const unsigned long long b = emask[c * NEXP + q];
            if ((b >> lane) & 1ULL) { e = q; mm = b; }
        }
        const int bexc = (c > 0) ? pre[(c - 1) * NEXP + e] : 0;
        const int rank = bexc + (int)__popcll(mm & below);
        int* rout = (k == 0 ? r1 : r2);
        if (rank < cap) {
            rout[n] = rank;
            slot_token[(size_t)e * cap + rank] = (p > 0.0f) ? n : -1;
        } else {
            rout[n] = -1;
        }
    }
}

// ---------------------------------------------------------------------------
// Kernel 3: fused fill. One wave per output row.
//   rows [0, N*E):           expert_weights + expert_mask row (length cap)
//   rows [N*E, N*E + E*cap): expert_batches row (length D)
// Inner loop: 1 compare + vector cndmask per 16B pair — near-pure streaming.
// ---------------------------------------------------------------------------
__global__ __launch_bounds__(256) void k_fill(
    const int* __restrict__ e1, const int* __restrict__ e2,
    const float* __restrict__ p1, const float* __restrict__ p2,
    const int* __restrict__ r1, const int* __restrict__ r2,
    const int* __restrict__ slot_token, const float* __restrict__ x,
    float* __restrict__ W, float* __restrict__ M, float* __restrict__ Bt,
    int cap, int N, int nrows)
{
    const int wave = threadIdx.x >> 6, lane = threadIdx.x & 63;
    const int row = blockIdx.x * 4 + wave;
    if (row >= nrows) return;

    const int nwm = N * NEXP;
    if (row < nwm) {
        const int n = row >> 3, e = row & 7;
        float p = 0.0f; int r = -1;
        if (e == e1[n])      { r = r1[n]; p = p1[n]; }
        else if (e == e2[n]) { r = r2[n]; p = p2[n]; }

        const float mval = (r >= 0 && p > 0.0f) ? 1.0f : 0.0f;
        const float wval = (r >= 0) ? p : 0.0f;
        const int t = (r >= 0) ? (r >> 2) : -1;   // float4 index holding r
        const int q = r & 3;
        const fv4 z = {0.f, 0.f, 0.f, 0.f};
        fv4 wj = z, mj = z;
        if (q == 0)      { wj.x = wval; mj.x = mval; }
        else if (q == 1) { wj.y = wval; mj.y = mval; }
        else if (q == 2) { wj.z = wval; mj.z = mval; }
        else             { wj.w = wval; mj.w = mval; }

        fv4* Wr = (fv4*)(W + (size_t)row * cap);
        fv4* Mr = (fv4*)(M + (size_t)row * cap);
        const int nf4 = cap >> 2;
        for (int c4 = lane; c4 < nf4; c4 += 64) {
            const bool hit = (c4 == t);
            Wr[c4] = hit ? wj : z;
            Mr[c4] = hit ? mj : z;
        }
    } else {
        const int brow = row - nwm;               // e*cap + slot
        const int tok = slot_token[brow];
        fv4* out = (fv4*)(Bt + (size_t)brow * DIM);
        if (tok >= 0) {
            const fv4* src = (const fv4*)(x + (size_t)tok * DIM);
#pragma unroll
            for (int i = 0; i < 4; ++i) out[lane + 64 * i] = src[lane + 64 * i];
        } else {
            const fv4 z = {0.f, 0.f, 0.f, 0.f};
#pragma unroll
            for (int i = 0; i < 4; ++i) out[lane + 64 * i] = z;
        }
    }
}

// ---------------------------------------------------------------------------
extern "C" void kernel_launch(void* const* d_in, const int* in_sizes, int n_in,
                              void* d_out, int out_size, void* d_ws, size_t ws_size,
                              hipStream_t stream)
{
    const float* x  = (const float*)d_in[0];
    const float* wg = (const float*)d_in[1];

    const int N = in_sizes[0] / DIM;          // 4096 tokens
    int cap = (5 * N) / 16;                   // floor(2*1.25*N/8)
    cap += cap & 1;
    if (cap < 2) cap = 2;

    // output layout: W [N,E,cap] | M [N,E,cap] | Bt [E,cap,D] | L [N,E]
    const size_t szW = (size_t)N * NEXP * cap;
    float* W  = (float*)d_out;
    float* M  = W + szW;
    float* Bt = M + szW;
    float* L  = Bt + (size_t)NEXP * cap * DIM;

    // workspace carve-up
    char* w = (char*)d_ws;
    int*   e1 = (int*)w;        w += (size_t)N * sizeof(int);
    int*   e2 = (int*)w;        w += (size_t)N * sizeof(int);
    float* p1 = (float*)w;      w += (size_t)N * sizeof(float);
    float* p2 = (float*)w;      w += (size_t)N * sizeof(float);
    int*   r1 = (int*)w;        w += (size_t)N * sizeof(int);
    int*   r2 = (int*)w;        w += (size_t)N * sizeof(int);
    int*   slot_token = (int*)w;

    k_router<<<(N + 15) / 16, 256, 0, stream>>>(x, wg, L, e1, e2, p1, p2, N);
    k_scan<<<1, 1024, 0, stream>>>(e1, e2, p1, p2, r1, r2, slot_token, N, cap);
    const int nrows = N * NEXP + NEXP * cap;
    k_fill<<<(nrows + 3) / 4, 256, 0, stream>>>(e1, e2, p1, p2, r1, r2,
                                                slot_token, x, W, M, Bt,
                                                cap, N, nrows);
}